// Round 15
// baseline (1019.113 us; speedup 1.0000x reference)
//
#include <hip/hip_runtime.h>
#include <hip/hip_cooperative_groups.h>
#include <math.h>

namespace cg = cooperative_groups;

#define NSCALE 0.44668359215096315f

typedef float v2f __attribute__((ext_vector_type(2)));

__device__ __forceinline__ v2f fma2(v2f a, v2f b, v2f c) { return __builtin_elementwise_fma(a, b, c); }
__device__ __forceinline__ v2f s2(float w) { v2f r = {w, w}; return r; }
__device__ __forceinline__ v2f max0(v2f v) { v2f z = {0.0f, 0.0f}; return __builtin_elementwise_max(v, z); }
__device__ __forceinline__ float eluf(float v)  { return v > 0.0f ? v : __expf(v) - 1.0f; }
__device__ __forceinline__ float reluf(float v) { return fmaxf(v, 0.0f); }

__device__ __forceinline__ float dot16p(const float* __restrict__ w, const v2f p[8], float b) {
    const v2f* w2 = reinterpret_cast<const v2f*>(w);
    v2f a = {b, 0.0f};
#pragma unroll
    for (int q = 0; q < 8; ++q) a = fma2(w2[q], p[q], a);
    return a.x + a.y;
}
__device__ __forceinline__ float dot32p(const float* __restrict__ w, const v2f p[16], float b) {
    const v2f* w2 = reinterpret_cast<const v2f*>(w);
    v2f a = {b, 0.0f};
#pragma unroll
    for (int q = 0; q < 16; ++q) a = fma2(w2[q], p[q], a);
    return a.x + a.y;
}
__device__ __forceinline__ float dot8p(const float* __restrict__ w, const v2f p[4], float b) {
    const v2f* w2 = reinterpret_cast<const v2f*>(w);
    v2f a = {b, 0.0f};
#pragma unroll
    for (int q = 0; q < 4; ++q) a = fma2(w2[q], p[q], a);
    return a.x + a.y;
}

// ===================== shared device bodies =====================

__device__ __forceinline__ void swizzle_weights(int tid,
    const float* __restrict__ pc1w, const float* __restrict__ pc2w,
    const float* __restrict__ pc5w, const float* __restrict__ dl1w,
    float* __restrict__ pc1i, float* __restrict__ pc2s,
    float* __restrict__ pc5s, float* __restrict__ dl1s)
{
    for (int n = tid; n < 64; n += 256) {             // pc1w[o][k] -> pc1i[j][k][{2j,2j+1}]
        int j = n >> 3, k = (n >> 1) & 3, h = n & 1;
        pc1i[n] = pc1w[(2*j + h)*4 + k];
    }
    for (int j = tid; j < 512; j += 256) {            // pc2w[o*32+ci*2+tap] -> [tap][o][ci]
        int o = j >> 5, r = j & 31, ci = r >> 1, tap = r & 1;
        pc2s[tap*256 + o*16 + ci] = pc2w[j];
    }
    for (int j = tid; j < 768; j += 256) {            // pc5w[o*48+ci*3+g] -> [g][o][ci]
        int o = j / 48, r = j - o*48, ci = r / 3, g = r - ci*3;
        pc5s[g*256 + o*16 + ci] = pc5w[j];
    }
    for (int j = tid; j < 1024; j += 256) {           // dl1w[o*64+c*8+t] -> [t][o][c]
        int o = j >> 6, r = j & 63, c = r >> 3, t = r & 7;
        dl1s[t*128 + o*8 + c] = dl1w[j];
    }
}

// encoder for element i (x -> z[16]); zeroed if !valid
__device__ __forceinline__ void encoder_z(const float* __restrict__ x, int i, bool valid,
                                          const float* __restrict__ ew1, const float* __restrict__ eb1,
                                          const float* __restrict__ ew2, const float* __restrict__ eb2,
                                          float z[16])
{
    v2f x2[8];
    if (valid) {
        const float4* xp = reinterpret_cast<const float4*>(x + (size_t)i * 16);
#pragma unroll
        for (int q = 0; q < 4; ++q) {
            float4 v = xp[q];
            x2[2*q+0] = {v.x, v.y};
            x2[2*q+1] = {v.z, v.w};
        }
    } else {
#pragma unroll
        for (int q = 0; q < 8; ++q) x2[q] = {0.0f, 0.0f};
    }
    v2f h1p[8];
#pragma unroll
    for (int j = 0; j < 8; ++j) {
        float r0 = eluf(dot16p(ew1 + (2*j+0)*16, x2, eb1[2*j+0]));
        float r1 = eluf(dot16p(ew1 + (2*j+1)*16, x2, eb1[2*j+1]));
        h1p[j] = {r0, r1};
    }
#pragma unroll
    for (int o = 0; o < 16; ++o) {
        float a = dot16p(ew2 + o*16, h1p, eb2[o]);
        z[o] = valid ? a : 0.0f;
    }
}

// per-block stats: z -> partials[chunk*32..]
__device__ __forceinline__ void block_stats(const float z[16], int tid, int chunk,
                                            float wsum[4][32], float* __restrict__ partials)
{
    int lane = tid & 63, wave = tid >> 6;
#pragma unroll
    for (int c = 0; c < 16; ++c) {
        float s = z[c];
        float q = z[c] * z[c];
#pragma unroll
        for (int m = 1; m < 64; m <<= 1) { s += __shfl_xor(s, m); q += __shfl_xor(q, m); }
        if (lane == 0) { wsum[wave][c] = s; wsum[wave][16 + c] = q; }
    }
    __syncthreads();
    if (tid < 32) {
        float t = wsum[0][tid] + wsum[1][tid] + wsum[2][tid] + wsum[3][tid];
        partials[(size_t)chunk * 32 + tid] = t;
    }
    __syncthreads();
}

// main pipeline body for element i: z -> out (r11-proven structure)
__device__ __forceinline__ void pipeline_body(int i, const float z[16],
    float* __restrict__ crt,
    const float* __restrict__ fading, const float* __restrict__ noise,
    const float* __restrict__ bnp,
    const float* __restrict__ pc1i, const float* __restrict__ pc1b,
    const float* __restrict__ pc2s, const float* __restrict__ pc2b,
    const float* __restrict__ pc3w, const float* __restrict__ pc3b,
    const float* __restrict__ pc4w, const float* __restrict__ pc4b,
    const float* __restrict__ pc5s, const float* __restrict__ pc5b,
    const float* __restrict__ plw,  const float* __restrict__ plb,
    const float* __restrict__ dc1w, const float* __restrict__ dc1b,
    const float* __restrict__ dc2w, const float* __restrict__ dc2b,
    const float* __restrict__ dc3w, const float* __restrict__ dc3b,
    const float* __restrict__ dc4w, const float* __restrict__ dc4b,
    const float* __restrict__ dl1s, const float* __restrict__ dl1b,
    const float* __restrict__ dl2w, const float* __restrict__ dl2b,
    const float* __restrict__ dl3w, const float* __restrict__ dl3b,
    float* __restrict__ out)
{
    // ---- BN affine + FIR + noise; cr stays live through the equalizer ----
    float cr[16];
    {
        float zn[16];
#pragma unroll
        for (int o = 0; o < 16; ++o) zn[o] = fmaf(z[o], bnp[o], bnp[16 + o]);
        float f[6];
        const float2* fp = reinterpret_cast<const float2*>(fading + (size_t)i * 6);
#pragma unroll
        for (int q = 0; q < 3; ++q) { float2 v = fp[q]; f[2*q] = v.x; f[2*q+1] = v.y; }
#pragma unroll
        for (int n = 0; n < 8; ++n) {
            float re = f[0]*zn[2*n]   - f[1]*zn[2*n+1];
            float im = f[0]*zn[2*n+1] + f[1]*zn[2*n];
            if (n >= 1) { re += f[2]*zn[2*n-2] - f[3]*zn[2*n-1];
                          im += f[2]*zn[2*n-1] + f[3]*zn[2*n-2]; }
            if (n >= 2) { re += f[4]*zn[2*n-4] - f[5]*zn[2*n-3];
                          im += f[4]*zn[2*n-3] + f[5]*zn[2*n-4]; }
            cr[2*n] = re; cr[2*n+1] = im;
        }
        const float4* np_ = reinterpret_cast<const float4*>(noise + (size_t)i * 16);
#pragma unroll
        for (int q = 0; q < 4; ++q) {
            float4 v = np_[q];
            cr[4*q+0] = fmaf(v.x, NSCALE, cr[4*q+0]);
            cr[4*q+1] = fmaf(v.y, NSCALE, cr[4*q+1]);
            cr[4*q+2] = fmaf(v.z, NSCALE, cr[4*q+2]);
            cr[4*q+3] = fmaf(v.w, NSCALE, cr[4*q+3]);
        }
        float4* op = reinterpret_cast<float4*>(crt + (size_t)i * 16);
        op[0] = make_float4(cr[0],  cr[1],  cr[2],  cr[3]);
        op[1] = make_float4(cr[4],  cr[5],  cr[6],  cr[7]);
        op[2] = make_float4(cr[8],  cr[9],  cr[10], cr[11]);
        op[3] = make_float4(cr[12], cr[13], cr[14], cr[15]);
    }

    // ---- p-convs, packed; p5 accumulates as v2f across g (rolled) ----
    v2f p5acc[16];
#pragma unroll
    for (int o = 0; o < 16; ++o) p5acc[o] = {pc5b[o], 0.0f};

#pragma unroll 1
    for (int g = 0; g < 3; ++g) {
        float crg[8];
        {
            const float4* cp = reinterpret_cast<const float4*>(crt + (size_t)i * 16 + 4 * g);
            float4 v0 = cp[0], v1 = cp[1];
            crg[0]=v0.x; crg[1]=v0.y; crg[2]=v0.z; crg[3]=v0.w;
            crg[4]=v1.x; crg[5]=v1.y; crg[6]=v1.z; crg[7]=v1.w;
        }
        v2f p1p[3][8];
#pragma unroll
        for (int c2 = 0; c2 < 3; ++c2) {
#pragma unroll
            for (int j = 0; j < 8; ++j) {
                const v2f* wi = reinterpret_cast<const v2f*>(pc1i + j*8);
                v2f a = *reinterpret_cast<const v2f*>(pc1b + 2*j);
                a = fma2(wi[0], s2(crg[c2+0]), a);
                a = fma2(wi[1], s2(crg[c2+1]), a);
                a = fma2(wi[2], s2(crg[c2+2]), a);
                a = fma2(wi[3], s2(crg[c2+3]), a);
                p1p[c2][j] = max0(a);
            }
        }
        v2f p2pair[16];
#pragma unroll
        for (int o = 0; o < 16; ++o) {
            const v2f* w0 = reinterpret_cast<const v2f*>(pc2s + o*16);
            const v2f* w1 = reinterpret_cast<const v2f*>(pc2s + 256 + o*16);
            v2f a0 = {pc2b[o], 0.0f}, a1 = {pc2b[o], 0.0f};
#pragma unroll
            for (int q = 0; q < 8; ++q) {
                v2f v0 = w0[q], v1 = w1[q];
                a0 = fma2(v0, p1p[0][q], a0);
                a0 = fma2(v1, p1p[1][q], a0);
                a1 = fma2(v0, p1p[1][q], a1);
                a1 = fma2(v1, p1p[2][q], a1);
            }
            p2pair[o] = {reluf(a0.x + a0.y), reluf(a1.x + a1.y)};
        }
        v2f p3p[8];
#pragma unroll
        for (int j = 0; j < 8; ++j) {
            float r0 = reluf(dot32p(pc3w + (2*j+0)*32, p2pair, pc3b[2*j+0]));
            float r1 = reluf(dot32p(pc3w + (2*j+1)*32, p2pair, pc3b[2*j+1]));
            p3p[j] = {r0, r1};
        }
        v2f p4p[8];
#pragma unroll
        for (int j = 0; j < 8; ++j) {
            float r0 = reluf(dot16p(pc4w + (2*j+0)*16, p3p, pc4b[2*j+0]));
            float r1 = reluf(dot16p(pc4w + (2*j+1)*16, p3p, pc4b[2*j+1]));
            p4p[j] = {r0, r1};
        }
#pragma unroll
        for (int o = 0; o < 16; ++o) {
            const v2f* w = reinterpret_cast<const v2f*>(pc5s + g*256 + o*16);
            v2f a = p5acc[o];
#pragma unroll
            for (int q = 0; q < 8; ++q) a = fma2(w[q], p4p[q], a);
            p5acc[o] = a;
        }
    }

    // pl
    v2f p5p[8];
#pragma unroll
    for (int j = 0; j < 8; ++j) {
        float r0 = reluf(p5acc[2*j+0].x + p5acc[2*j+0].y);
        float r1 = reluf(p5acc[2*j+1].x + p5acc[2*j+1].y);
        p5p[j] = {r0, r1};
    }
    float hh[16];
#pragma unroll
    for (int o = 0; o < 16; ++o) hh[o] = dot16p(plw + o*16, p5p, plb[o]);

    // equalizer — cr still live, tr stays in registers
    float tr[16];
#pragma unroll
    for (int n = 0; n < 8; ++n) {
        float a = cr[2*n], b = cr[2*n+1];
        float c = hh[2*n], d = hh[2*n+1];
        float inv = 1.0f / (c*c + d*d);
        tr[2*n]   = (a*c + b*d) * inv;
        tr[2*n+1] = (b*c - a*d) * inv;
    }

    // ---- decoder: fully unrolled t-loop, tr in registers ----
    v2f y2[16];
#pragma unroll
    for (int o = 0; o < 16; ++o) y2[o] = {dl1b[o], 0.0f};

#pragma unroll
    for (int t = 0; t < 8; ++t) {
        v2f tv2 = {tr[2*t], tr[2*t+1]};
        v2f d1p[8];
#pragma unroll
        for (int c = 0; c < 8; ++c) {
            d1p[c] = max0(fma2(s2(dc1w[c]), tv2, s2(dc1b[c])));
        }
        v2f d2p[4];
#pragma unroll
        for (int j = 0; j < 4; ++j) {
            float r0 = reluf(dot16p(dc2w + (2*j+0)*16, d1p, dc2b[2*j+0]));
            float r1 = reluf(dot16p(dc2w + (2*j+1)*16, d1p, dc2b[2*j+1]));
            d2p[j] = {r0, r1};
        }
        v2f d3p[4];
#pragma unroll
        for (int j = 0; j < 4; ++j) {
            float r0 = reluf(dot8p(dc3w + (2*j+0)*8, d2p, dc3b[2*j+0]));
            float r1 = reluf(dot8p(dc3w + (2*j+1)*8, d2p, dc3b[2*j+1]));
            d3p[j] = {r0, r1};
        }
        v2f d4p[4];
#pragma unroll
        for (int j = 0; j < 4; ++j) {
            float r0 = reluf(dot8p(dc4w + (2*j+0)*8, d3p, dc4b[2*j+0]));
            float r1 = reluf(dot8p(dc4w + (2*j+1)*8, d3p, dc4b[2*j+1]));
            d4p[j] = {r0, r1};
        }
#pragma unroll
        for (int o = 0; o < 16; ++o) {
            const v2f* w = reinterpret_cast<const v2f*>(dl1s + t*128 + o*8);
            v2f a = y2[o];
#pragma unroll
            for (int q = 0; q < 4; ++q) a = fma2(w[q], d4p[q], a);
            y2[o] = a;
        }
    }

    v2f yp[8];
#pragma unroll
    for (int j = 0; j < 8; ++j) {
        float r0 = reluf(y2[2*j+0].x + y2[2*j+0].y);
        float r1 = reluf(y2[2*j+1].x + y2[2*j+1].y);
        yp[j] = {r0, r1};
    }
    v2f h2p[8];
#pragma unroll
    for (int j = 0; j < 8; ++j) {
        float r0 = eluf(dot16p(dl2w + (2*j+0)*16, yp, dl2b[2*j+0]));
        float r1 = eluf(dot16p(dl2w + (2*j+1)*16, yp, dl2b[2*j+1]));
        h2p[j] = {r0, r1};
    }
    float o16[16];
#pragma unroll
    for (int o = 0; o < 16; ++o) o16[o] = dot16p(dl3w + o*16, h2p, dl3b[o]);

    float4* op = reinterpret_cast<float4*>(out + (size_t)i * 16);
    op[0] = make_float4(o16[0],  o16[1],  o16[2],  o16[3]);
    op[1] = make_float4(o16[4],  o16[5],  o16[6],  o16[7]);
    op[2] = make_float4(o16[8],  o16[9],  o16[10], o16[11]);
    op[3] = make_float4(o16[12], o16[13], o16[14], o16[15]);
}

// ===================== cooperative fused kernel =====================
__global__ __launch_bounds__(256, 4) void kFC(
    const float* __restrict__ x, const float* __restrict__ noise, const float* __restrict__ fading,
    const float* __restrict__ ew1, const float* __restrict__ eb1,
    const float* __restrict__ ew2, const float* __restrict__ eb2,
    const float* __restrict__ bng, const float* __restrict__ bnb,
    const float* __restrict__ pc1w, const float* __restrict__ pc1b,
    const float* __restrict__ pc2w, const float* __restrict__ pc2b,
    const float* __restrict__ pc3w, const float* __restrict__ pc3b,
    const float* __restrict__ pc4w, const float* __restrict__ pc4b,
    const float* __restrict__ pc5w, const float* __restrict__ pc5b,
    const float* __restrict__ plw,  const float* __restrict__ plb,
    const float* __restrict__ dc1w, const float* __restrict__ dc1b,
    const float* __restrict__ dc2w, const float* __restrict__ dc2b,
    const float* __restrict__ dc3w, const float* __restrict__ dc3b,
    const float* __restrict__ dc4w, const float* __restrict__ dc4b,
    const float* __restrict__ dl1w, const float* __restrict__ dl1b,
    const float* __restrict__ dl2w, const float* __restrict__ dl2b,
    const float* __restrict__ dl3w, const float* __restrict__ dl3b,
    float* __restrict__ out,
    float* __restrict__ partials, float* __restrict__ bnp,
    float* __restrict__ pc1i, float* __restrict__ pc2s,
    float* __restrict__ pc5s, float* __restrict__ dl1s,
    float* __restrict__ crt,
    int B, int nblk)
{
    int tid = threadIdx.x;
    int bid = blockIdx.x;
    int gsz = gridDim.x;
    bool multi = nblk > gsz;
    cg::grid_group gg = cg::this_grid();

    __shared__ float wsum[4][32];
    __shared__ double tot[32];

    float zr[16];

    // phase 1: encoder + stats (+ optional z spill in multi mode)
    for (int chunk = bid; chunk < nblk; chunk += gsz) {
        int i = chunk * 256 + tid;
        bool valid = i < B;
        encoder_z(x, i, valid, ew1, eb1, ew2, eb2, zr);
        if (multi && valid) {
            float4* zp = reinterpret_cast<float4*>(crt + (size_t)i * 16);
            zp[0] = make_float4(zr[0],  zr[1],  zr[2],  zr[3]);
            zp[1] = make_float4(zr[4],  zr[5],  zr[6],  zr[7]);
            zp[2] = make_float4(zr[8],  zr[9],  zr[10], zr[11]);
            zp[3] = make_float4(zr[12], zr[13], zr[14], zr[15]);
        }
        block_stats(zr, tid, chunk, wsum, partials);
    }
    if (bid == 0) swizzle_weights(tid, pc1w, pc2w, pc5w, dl1w, pc1i, pc2s, pc5s, dl1s);

    gg.sync();

    // phase 2: block 0 reduces partials -> bnp
    if (bid == 0) {
        int q = tid >> 3, k = tid & 7;
        int chunk = (nblk + 7) / 8;
        int j0 = k * chunk;
        int j1 = j0 + chunk; if (j1 > nblk) j1 = nblk;
        double s = 0.0;
        for (int j = j0; j < j1; ++j) s += (double)partials[(size_t)j * 32 + q];
        s += __shfl_xor(s, 4);
        s += __shfl_xor(s, 2);
        s += __shfl_xor(s, 1);
        if (k == 0) tot[q] = s;
        __syncthreads();
        if (tid < 16) {
            double mu  = tot[tid] / (double)B;
            double var = tot[16 + tid] / (double)B - mu * mu;
            double a = (double)bng[tid] / sqrt(var + 1e-5);
            double b = (double)bnb[tid] - mu * a;
            bnp[tid]      = (float)a;
            bnp[16 + tid] = (float)b;
        }
    }

    gg.sync();

    // phase 3: main pipeline (z from registers in non-multi mode)
    for (int chunk = bid; chunk < nblk; chunk += gsz) {
        int i = chunk * 256 + tid;
        if (i >= B) continue;
        float z[16];
        if (multi) {
            const float4* zp = reinterpret_cast<const float4*>(crt + (size_t)i * 16);
#pragma unroll
            for (int q = 0; q < 4; ++q) {
                float4 v = zp[q];
                z[4*q+0] = v.x; z[4*q+1] = v.y; z[4*q+2] = v.z; z[4*q+3] = v.w;
            }
        } else {
#pragma unroll
            for (int o = 0; o < 16; ++o) z[o] = zr[o];
        }
        pipeline_body(i, z, crt, fading, noise, bnp,
                      pc1i, pc1b, pc2s, pc2b, pc3w, pc3b, pc4w, pc4b, pc5s, pc5b,
                      plw, plb, dc1w, dc1b, dc2w, dc2b, dc3w, dc3b, dc4w, dc4b,
                      dl1s, dl1b, dl2w, dl2b, dl3w, dl3b, out);
    }
}

// ===================== fallback 3-kernel path (r14, proven 225 us) =====================

__global__ __launch_bounds__(256) void kAW(const float* __restrict__ x,
                                           const float* __restrict__ ew1, const float* __restrict__ eb1,
                                           const float* __restrict__ ew2, const float* __restrict__ eb2,
                                           float* __restrict__ partials, float* __restrict__ zout, int B,
                                           const float* __restrict__ pc1w, const float* __restrict__ pc2w,
                                           const float* __restrict__ pc5w, const float* __restrict__ dl1w,
                                           float* __restrict__ pc1i, float* __restrict__ pc2s,
                                           float* __restrict__ pc5s, float* __restrict__ dl1s)
{
    int tid = threadIdx.x;
    if (blockIdx.x == gridDim.x - 1) {
        swizzle_weights(tid, pc1w, pc2w, pc5w, dl1w, pc1i, pc2s, pc5s, dl1s);
        return;
    }
    __shared__ float wsum[4][32];
    int i = blockIdx.x * 256 + tid;
    bool valid = i < B;
    float z[16];
    encoder_z(x, i, valid, ew1, eb1, ew2, eb2, z);
    if (valid) {
        float4* zp = reinterpret_cast<float4*>(zout + (size_t)i * 16);
        zp[0] = make_float4(z[0],  z[1],  z[2],  z[3]);
        zp[1] = make_float4(z[4],  z[5],  z[6],  z[7]);
        zp[2] = make_float4(z[8],  z[9],  z[10], z[11]);
        zp[3] = make_float4(z[12], z[13], z[14], z[15]);
    }
    block_stats(z, tid, blockIdx.x, wsum, partials);
}

__global__ __launch_bounds__(256) void kB(const float* __restrict__ partials, int nblk, int B,
                                          const float* __restrict__ bng, const float* __restrict__ bnb,
                                          float* __restrict__ bnp)
{
    int tid = threadIdx.x;
    int q = tid >> 3, k = tid & 7;
    int chunk = (nblk + 7) / 8;
    int j0 = k * chunk;
    int j1 = j0 + chunk; if (j1 > nblk) j1 = nblk;
    double s = 0.0;
    for (int j = j0; j < j1; ++j) s += (double)partials[(size_t)j * 32 + q];
    s += __shfl_xor(s, 4);
    s += __shfl_xor(s, 2);
    s += __shfl_xor(s, 1);
    __shared__ double tot[32];
    if (k == 0) tot[q] = s;
    __syncthreads();
    if (tid < 16) {
        double mu  = tot[tid] / (double)B;
        double var = tot[16 + tid] / (double)B - mu * mu;
        double a = (double)bng[tid] / sqrt(var + 1e-5);
        double b = (double)bnb[tid] - mu * a;
        bnp[tid]      = (float)a;
        bnp[16 + tid] = (float)b;
    }
}

__global__ __launch_bounds__(256) void kF(float* __restrict__ crt,
    const float* __restrict__ fading, const float* __restrict__ noise,
    const float* __restrict__ bnp,
    const float* __restrict__ pc1i, const float* __restrict__ pc1b,
    const float* __restrict__ pc2s, const float* __restrict__ pc2b,
    const float* __restrict__ pc3w, const float* __restrict__ pc3b,
    const float* __restrict__ pc4w, const float* __restrict__ pc4b,
    const float* __restrict__ pc5s, const float* __restrict__ pc5b,
    const float* __restrict__ plw,  const float* __restrict__ plb,
    const float* __restrict__ dc1w, const float* __restrict__ dc1b,
    const float* __restrict__ dc2w, const float* __restrict__ dc2b,
    const float* __restrict__ dc3w, const float* __restrict__ dc3b,
    const float* __restrict__ dc4w, const float* __restrict__ dc4b,
    const float* __restrict__ dl1s, const float* __restrict__ dl1b,
    const float* __restrict__ dl2w, const float* __restrict__ dl2b,
    const float* __restrict__ dl3w, const float* __restrict__ dl3b,
    float* __restrict__ out, int B)
{
    int i = blockIdx.x * 256 + threadIdx.x;
    if (i >= B) return;
    float z[16];
    {
        const float4* zp = reinterpret_cast<const float4*>(crt + (size_t)i * 16);
#pragma unroll
        for (int q = 0; q < 4; ++q) {
            float4 v = zp[q];
            z[4*q+0] = v.x; z[4*q+1] = v.y; z[4*q+2] = v.z; z[4*q+3] = v.w;
        }
    }
    pipeline_body(i, z, crt, fading, noise, bnp,
                  pc1i, pc1b, pc2s, pc2b, pc3w, pc3b, pc4w, pc4b, pc5s, pc5b,
                  plw, plb, dc1w, dc1b, dc2w, dc2b, dc3w, dc3b, dc4w, dc4b,
                  dl1s, dl1b, dl2w, dl2b, dl3w, dl3b, out);
}

extern "C" void kernel_launch(void* const* d_in, const int* in_sizes, int n_in,
                              void* d_out, int out_size, void* d_ws, size_t ws_size,
                              hipStream_t stream)
{
    const float* x      = (const float*)d_in[0];
    const float* noise  = (const float*)d_in[1];
    const float* fading = (const float*)d_in[2];
    const float* ew1  = (const float*)d_in[3];
    const float* eb1  = (const float*)d_in[4];
    const float* ew2  = (const float*)d_in[5];
    const float* eb2  = (const float*)d_in[6];
    const float* bng  = (const float*)d_in[7];
    const float* bnb  = (const float*)d_in[8];
    const float* pc1w = (const float*)d_in[9];
    const float* pc1b = (const float*)d_in[10];
    const float* pc2w = (const float*)d_in[11];
    const float* pc2b = (const float*)d_in[12];
    const float* pc3w = (const float*)d_in[13];
    const float* pc3b = (const float*)d_in[14];
    const float* pc4w = (const float*)d_in[15];
    const float* pc4b = (const float*)d_in[16];
    const float* pc5w = (const float*)d_in[17];
    const float* pc5b = (const float*)d_in[18];
    const float* plw  = (const float*)d_in[19];
    const float* plb  = (const float*)d_in[20];
    const float* dc1w = (const float*)d_in[21];
    const float* dc1b = (const float*)d_in[22];
    const float* dc2w = (const float*)d_in[23];
    const float* dc2b = (const float*)d_in[24];
    const float* dc3w = (const float*)d_in[25];
    const float* dc3b = (const float*)d_in[26];
    const float* dc4w = (const float*)d_in[27];
    const float* dc4b = (const float*)d_in[28];
    const float* dl1w = (const float*)d_in[29];
    const float* dl1b = (const float*)d_in[30];
    const float* dl2w = (const float*)d_in[31];
    const float* dl2b = (const float*)d_in[32];
    const float* dl3w = (const float*)d_in[33];
    const float* dl3b = (const float*)d_in[34];

    int B = in_sizes[0] / 16;
    int nblk = (B + 255) / 256;
    int grid = nblk < 1024 ? nblk : 1024;

    float* partials = (float*)d_ws;                    // nblk*32
    float* bnp  = partials + (size_t)nblk * 32;        // 32
    float* pc2s = bnp + 32;                            // 512
    float* pc5s = pc2s + 512;                          // 768
    float* dl1s = pc5s + 768;                          // 1024
    float* pc1i = dl1s + 1024;                         // 128
    float* crt  = pc1i + 128;                          // B*16

    float* outp = (float*)d_out;

    void* params[] = {
        (void*)&x, (void*)&noise, (void*)&fading,
        (void*)&ew1, (void*)&eb1, (void*)&ew2, (void*)&eb2,
        (void*)&bng, (void*)&bnb,
        (void*)&pc1w, (void*)&pc1b, (void*)&pc2w, (void*)&pc2b,
        (void*)&pc3w, (void*)&pc3b, (void*)&pc4w, (void*)&pc4b,
        (void*)&pc5w, (void*)&pc5b, (void*)&plw, (void*)&plb,
        (void*)&dc1w, (void*)&dc1b, (void*)&dc2w, (void*)&dc2b,
        (void*)&dc3w, (void*)&dc3b, (void*)&dc4w, (void*)&dc4b,
        (void*)&dl1w, (void*)&dl1b, (void*)&dl2w, (void*)&dl2b,
        (void*)&dl3w, (void*)&dl3b,
        (void*)&outp,
        (void*)&partials, (void*)&bnp,
        (void*)&pc1i, (void*)&pc2s, (void*)&pc5s, (void*)&dl1s,
        (void*)&crt,
        (void*)&B, (void*)&nblk
    };

    hipError_t err = hipLaunchCooperativeKernel((void*)kFC, dim3(grid), dim3(256),
                                                params, 0, stream);
    if (err != hipSuccess) {
        // deterministic fallback: proven 3-kernel path
        (void)hipGetLastError();   // clear sticky error
        kAW<<<nblk + 1, 256, 0, stream>>>(x, ew1, eb1, ew2, eb2, partials, crt, B,
                                          pc1w, pc2w, pc5w, dl1w,
                                          pc1i, pc2s, pc5s, dl1s);
        kB<<<1, 256, 0, stream>>>(partials, nblk, B, bng, bnb, bnp);
        kF<<<nblk, 256, 0, stream>>>(crt, fading, noise, bnp,
                                     pc1i, pc1b, pc2s, pc2b, pc3w, pc3b, pc4w, pc4b, pc5s, pc5b,
                                     plw, plb,
                                     dc1w, dc1b, dc2w, dc2b, dc3w, dc3b, dc4w, dc4b,
                                     dl1s, dl1b, dl2w, dl2b, dl3w, dl3b,
                                     (float*)d_out, B);
    }
}

// Round 16
// 223.660 us; speedup vs baseline: 4.5565x; 4.5565x over previous
//
#include <hip/hip_runtime.h>
#include <hip/hip_cooperative_groups.h>
#include <math.h>

namespace cg = cooperative_groups;

#define NSCALE 0.44668359215096315f

typedef float v2f __attribute__((ext_vector_type(2)));

__device__ __forceinline__ v2f fma2(v2f a, v2f b, v2f c) { return __builtin_elementwise_fma(a, b, c); }
__device__ __forceinline__ v2f s2(float w) { v2f r = {w, w}; return r; }
__device__ __forceinline__ v2f max0(v2f v) { v2f z = {0.0f, 0.0f}; return __builtin_elementwise_max(v, z); }
__device__ __forceinline__ float eluf(float v)  { return v > 0.0f ? v : __expf(v) - 1.0f; }
__device__ __forceinline__ float reluf(float v) { return fmaxf(v, 0.0f); }

__device__ __forceinline__ float dot16p(const float* __restrict__ w, const v2f p[8], float b) {
    const v2f* w2 = reinterpret_cast<const v2f*>(w);
    v2f a = {b, 0.0f};
#pragma unroll
    for (int q = 0; q < 8; ++q) a = fma2(w2[q], p[q], a);
    return a.x + a.y;
}
__device__ __forceinline__ float dot32p(const float* __restrict__ w, const v2f p[16], float b) {
    const v2f* w2 = reinterpret_cast<const v2f*>(w);
    v2f a = {b, 0.0f};
#pragma unroll
    for (int q = 0; q < 16; ++q) a = fma2(w2[q], p[q], a);
    return a.x + a.y;
}
__device__ __forceinline__ float dot8p(const float* __restrict__ w, const v2f p[4], float b) {
    const v2f* w2 = reinterpret_cast<const v2f*>(w);
    v2f a = {b, 0.0f};
#pragma unroll
    for (int q = 0; q < 4; ++q) a = fma2(w2[q], p[q], a);
    return a.x + a.y;
}

// ===================== shared device bodies =====================

__device__ __forceinline__ void swizzle_weights(int tid,
    const float* __restrict__ pc1w, const float* __restrict__ pc2w,
    const float* __restrict__ pc5w, const float* __restrict__ dl1w,
    float* __restrict__ pc1i, float* __restrict__ pc2s,
    float* __restrict__ pc5s, float* __restrict__ dl1s)
{
    for (int n = tid; n < 64; n += 256) {             // pc1w[o][k] -> pc1i[j][k][{2j,2j+1}]
        int j = n >> 3, k = (n >> 1) & 3, h = n & 1;
        pc1i[n] = pc1w[(2*j + h)*4 + k];
    }
    for (int j = tid; j < 512; j += 256) {            // pc2w[o*32+ci*2+tap] -> [tap][o][ci]
        int o = j >> 5, r = j & 31, ci = r >> 1, tap = r & 1;
        pc2s[tap*256 + o*16 + ci] = pc2w[j];
    }
    for (int j = tid; j < 768; j += 256) {            // pc5w[o*48+ci*3+g] -> [g][o][ci]
        int o = j / 48, r = j - o*48, ci = r / 3, g = r - ci*3;
        pc5s[g*256 + o*16 + ci] = pc5w[j];
    }
    for (int j = tid; j < 1024; j += 256) {           // dl1w[o*64+c*8+t] -> [t][o][c]
        int o = j >> 6, r = j & 63, c = r >> 3, t = r & 7;
        dl1s[t*128 + o*8 + c] = dl1w[j];
    }
}

// encoder for element i (x -> z[16]); zeroed if !valid
__device__ __forceinline__ void encoder_z(const float* __restrict__ x, int i, bool valid,
                                          const float* __restrict__ ew1, const float* __restrict__ eb1,
                                          const float* __restrict__ ew2, const float* __restrict__ eb2,
                                          float z[16])
{
    v2f x2[8];
    if (valid) {
        const float4* xp = reinterpret_cast<const float4*>(x + (size_t)i * 16);
#pragma unroll
        for (int q = 0; q < 4; ++q) {
            float4 v = xp[q];
            x2[2*q+0] = {v.x, v.y};
            x2[2*q+1] = {v.z, v.w};
        }
    } else {
#pragma unroll
        for (int q = 0; q < 8; ++q) x2[q] = {0.0f, 0.0f};
    }
    v2f h1p[8];
#pragma unroll
    for (int j = 0; j < 8; ++j) {
        float r0 = eluf(dot16p(ew1 + (2*j+0)*16, x2, eb1[2*j+0]));
        float r1 = eluf(dot16p(ew1 + (2*j+1)*16, x2, eb1[2*j+1]));
        h1p[j] = {r0, r1};
    }
#pragma unroll
    for (int o = 0; o < 16; ++o) {
        float a = dot16p(ew2 + o*16, h1p, eb2[o]);
        z[o] = valid ? a : 0.0f;
    }
}

// per-block stats: z -> partials[chunk*32..]
__device__ __forceinline__ void block_stats(const float z[16], int tid, int chunk,
                                            float wsum[4][32], float* __restrict__ partials)
{
    int lane = tid & 63, wave = tid >> 6;
#pragma unroll
    for (int c = 0; c < 16; ++c) {
        float s = z[c];
        float q = z[c] * z[c];
#pragma unroll
        for (int m = 1; m < 64; m <<= 1) { s += __shfl_xor(s, m); q += __shfl_xor(q, m); }
        if (lane == 0) { wsum[wave][c] = s; wsum[wave][16 + c] = q; }
    }
    __syncthreads();
    if (tid < 32) {
        float t = wsum[0][tid] + wsum[1][tid] + wsum[2][tid] + wsum[3][tid];
        partials[(size_t)chunk * 32 + tid] = t;
    }
    __syncthreads();
}

// main pipeline body for element i: z -> out (r11-proven structure)
__device__ __forceinline__ void pipeline_body(int i, const float z[16],
    float* __restrict__ crt,
    const float* __restrict__ fading, const float* __restrict__ noise,
    const float* __restrict__ bnp,
    const float* __restrict__ pc1i, const float* __restrict__ pc1b,
    const float* __restrict__ pc2s, const float* __restrict__ pc2b,
    const float* __restrict__ pc3w, const float* __restrict__ pc3b,
    const float* __restrict__ pc4w, const float* __restrict__ pc4b,
    const float* __restrict__ pc5s, const float* __restrict__ pc5b,
    const float* __restrict__ plw,  const float* __restrict__ plb,
    const float* __restrict__ dc1w, const float* __restrict__ dc1b,
    const float* __restrict__ dc2w, const float* __restrict__ dc2b,
    const float* __restrict__ dc3w, const float* __restrict__ dc3b,
    const float* __restrict__ dc4w, const float* __restrict__ dc4b,
    const float* __restrict__ dl1s, const float* __restrict__ dl1b,
    const float* __restrict__ dl2w, const float* __restrict__ dl2b,
    const float* __restrict__ dl3w, const float* __restrict__ dl3b,
    float* __restrict__ out)
{
    // ---- BN affine + FIR + noise; cr stays live through the equalizer ----
    float cr[16];
    {
        float zn[16];
#pragma unroll
        for (int o = 0; o < 16; ++o) zn[o] = fmaf(z[o], bnp[o], bnp[16 + o]);
        float f[6];
        const float2* fp = reinterpret_cast<const float2*>(fading + (size_t)i * 6);
#pragma unroll
        for (int q = 0; q < 3; ++q) { float2 v = fp[q]; f[2*q] = v.x; f[2*q+1] = v.y; }
#pragma unroll
        for (int n = 0; n < 8; ++n) {
            float re = f[0]*zn[2*n]   - f[1]*zn[2*n+1];
            float im = f[0]*zn[2*n+1] + f[1]*zn[2*n];
            if (n >= 1) { re += f[2]*zn[2*n-2] - f[3]*zn[2*n-1];
                          im += f[2]*zn[2*n-1] + f[3]*zn[2*n-2]; }
            if (n >= 2) { re += f[4]*zn[2*n-4] - f[5]*zn[2*n-3];
                          im += f[4]*zn[2*n-3] + f[5]*zn[2*n-4]; }
            cr[2*n] = re; cr[2*n+1] = im;
        }
        const float4* np_ = reinterpret_cast<const float4*>(noise + (size_t)i * 16);
#pragma unroll
        for (int q = 0; q < 4; ++q) {
            float4 v = np_[q];
            cr[4*q+0] = fmaf(v.x, NSCALE, cr[4*q+0]);
            cr[4*q+1] = fmaf(v.y, NSCALE, cr[4*q+1]);
            cr[4*q+2] = fmaf(v.z, NSCALE, cr[4*q+2]);
            cr[4*q+3] = fmaf(v.w, NSCALE, cr[4*q+3]);
        }
        float4* op = reinterpret_cast<float4*>(crt + (size_t)i * 16);
        op[0] = make_float4(cr[0],  cr[1],  cr[2],  cr[3]);
        op[1] = make_float4(cr[4],  cr[5],  cr[6],  cr[7]);
        op[2] = make_float4(cr[8],  cr[9],  cr[10], cr[11]);
        op[3] = make_float4(cr[12], cr[13], cr[14], cr[15]);
    }

    // ---- p-convs, packed; p5 accumulates as v2f across g (rolled) ----
    v2f p5acc[16];
#pragma unroll
    for (int o = 0; o < 16; ++o) p5acc[o] = {pc5b[o], 0.0f};

#pragma unroll 1
    for (int g = 0; g < 3; ++g) {
        float crg[8];
        {
            const float4* cp = reinterpret_cast<const float4*>(crt + (size_t)i * 16 + 4 * g);
            float4 v0 = cp[0], v1 = cp[1];
            crg[0]=v0.x; crg[1]=v0.y; crg[2]=v0.z; crg[3]=v0.w;
            crg[4]=v1.x; crg[5]=v1.y; crg[6]=v1.z; crg[7]=v1.w;
        }
        v2f p1p[3][8];
#pragma unroll
        for (int c2 = 0; c2 < 3; ++c2) {
#pragma unroll
            for (int j = 0; j < 8; ++j) {
                const v2f* wi = reinterpret_cast<const v2f*>(pc1i + j*8);
                v2f a = *reinterpret_cast<const v2f*>(pc1b + 2*j);
                a = fma2(wi[0], s2(crg[c2+0]), a);
                a = fma2(wi[1], s2(crg[c2+1]), a);
                a = fma2(wi[2], s2(crg[c2+2]), a);
                a = fma2(wi[3], s2(crg[c2+3]), a);
                p1p[c2][j] = max0(a);
            }
        }
        v2f p2pair[16];
#pragma unroll
        for (int o = 0; o < 16; ++o) {
            const v2f* w0 = reinterpret_cast<const v2f*>(pc2s + o*16);
            const v2f* w1 = reinterpret_cast<const v2f*>(pc2s + 256 + o*16);
            v2f a0 = {pc2b[o], 0.0f}, a1 = {pc2b[o], 0.0f};
#pragma unroll
            for (int q = 0; q < 8; ++q) {
                v2f v0 = w0[q], v1 = w1[q];
                a0 = fma2(v0, p1p[0][q], a0);
                a0 = fma2(v1, p1p[1][q], a0);
                a1 = fma2(v0, p1p[1][q], a1);
                a1 = fma2(v1, p1p[2][q], a1);
            }
            p2pair[o] = {reluf(a0.x + a0.y), reluf(a1.x + a1.y)};
        }
        v2f p3p[8];
#pragma unroll
        for (int j = 0; j < 8; ++j) {
            float r0 = reluf(dot32p(pc3w + (2*j+0)*32, p2pair, pc3b[2*j+0]));
            float r1 = reluf(dot32p(pc3w + (2*j+1)*32, p2pair, pc3b[2*j+1]));
            p3p[j] = {r0, r1};
        }
        v2f p4p[8];
#pragma unroll
        for (int j = 0; j < 8; ++j) {
            float r0 = reluf(dot16p(pc4w + (2*j+0)*16, p3p, pc4b[2*j+0]));
            float r1 = reluf(dot16p(pc4w + (2*j+1)*16, p3p, pc4b[2*j+1]));
            p4p[j] = {r0, r1};
        }
#pragma unroll
        for (int o = 0; o < 16; ++o) {
            const v2f* w = reinterpret_cast<const v2f*>(pc5s + g*256 + o*16);
            v2f a = p5acc[o];
#pragma unroll
            for (int q = 0; q < 8; ++q) a = fma2(w[q], p4p[q], a);
            p5acc[o] = a;
        }
    }

    // pl
    v2f p5p[8];
#pragma unroll
    for (int j = 0; j < 8; ++j) {
        float r0 = reluf(p5acc[2*j+0].x + p5acc[2*j+0].y);
        float r1 = reluf(p5acc[2*j+1].x + p5acc[2*j+1].y);
        p5p[j] = {r0, r1};
    }
    float hh[16];
#pragma unroll
    for (int o = 0; o < 16; ++o) hh[o] = dot16p(plw + o*16, p5p, plb[o]);

    // equalizer — cr still live, tr stays in registers
    float tr[16];
#pragma unroll
    for (int n = 0; n < 8; ++n) {
        float a = cr[2*n], b = cr[2*n+1];
        float c = hh[2*n], d = hh[2*n+1];
        float inv = 1.0f / (c*c + d*d);
        tr[2*n]   = (a*c + b*d) * inv;
        tr[2*n+1] = (b*c - a*d) * inv;
    }

    // ---- decoder: fully unrolled t-loop, tr in registers ----
    v2f y2[16];
#pragma unroll
    for (int o = 0; o < 16; ++o) y2[o] = {dl1b[o], 0.0f};

#pragma unroll
    for (int t = 0; t < 8; ++t) {
        v2f tv2 = {tr[2*t], tr[2*t+1]};
        v2f d1p[8];
#pragma unroll
        for (int c = 0; c < 8; ++c) {
            d1p[c] = max0(fma2(s2(dc1w[c]), tv2, s2(dc1b[c])));
        }
        v2f d2p[4];
#pragma unroll
        for (int j = 0; j < 4; ++j) {
            float r0 = reluf(dot16p(dc2w + (2*j+0)*16, d1p, dc2b[2*j+0]));
            float r1 = reluf(dot16p(dc2w + (2*j+1)*16, d1p, dc2b[2*j+1]));
            d2p[j] = {r0, r1};
        }
        v2f d3p[4];
#pragma unroll
        for (int j = 0; j < 4; ++j) {
            float r0 = reluf(dot8p(dc3w + (2*j+0)*8, d2p, dc3b[2*j+0]));
            float r1 = reluf(dot8p(dc3w + (2*j+1)*8, d2p, dc3b[2*j+1]));
            d3p[j] = {r0, r1};
        }
        v2f d4p[4];
#pragma unroll
        for (int j = 0; j < 4; ++j) {
            float r0 = reluf(dot8p(dc4w + (2*j+0)*8, d3p, dc4b[2*j+0]));
            float r1 = reluf(dot8p(dc4w + (2*j+1)*8, d3p, dc4b[2*j+1]));
            d4p[j] = {r0, r1};
        }
#pragma unroll
        for (int o = 0; o < 16; ++o) {
            const v2f* w = reinterpret_cast<const v2f*>(dl1s + t*128 + o*8);
            v2f a = y2[o];
#pragma unroll
            for (int q = 0; q < 4; ++q) a = fma2(w[q], d4p[q], a);
            y2[o] = a;
        }
    }

    v2f yp[8];
#pragma unroll
    for (int j = 0; j < 8; ++j) {
        float r0 = reluf(y2[2*j+0].x + y2[2*j+0].y);
        float r1 = reluf(y2[2*j+1].x + y2[2*j+1].y);
        yp[j] = {r0, r1};
    }
    v2f h2p[8];
#pragma unroll
    for (int j = 0; j < 8; ++j) {
        float r0 = eluf(dot16p(dl2w + (2*j+0)*16, yp, dl2b[2*j+0]));
        float r1 = eluf(dot16p(dl2w + (2*j+1)*16, yp, dl2b[2*j+1]));
        h2p[j] = {r0, r1};
    }
    float o16[16];
#pragma unroll
    for (int o = 0; o < 16; ++o) o16[o] = dot16p(dl3w + o*16, h2p, dl3b[o]);

    float4* op = reinterpret_cast<float4*>(out + (size_t)i * 16);
    op[0] = make_float4(o16[0],  o16[1],  o16[2],  o16[3]);
    op[1] = make_float4(o16[4],  o16[5],  o16[6],  o16[7]);
    op[2] = make_float4(o16[8],  o16[9],  o16[10], o16[11]);
    op[3] = make_float4(o16[12], o16[13], o16[14], o16[15]);
}

// ===================== cooperative fused kernel (natural VGPR — no min-waves clamp) =====================
__global__ __launch_bounds__(256) void kFC(
    const float* __restrict__ x, const float* __restrict__ noise, const float* __restrict__ fading,
    const float* __restrict__ ew1, const float* __restrict__ eb1,
    const float* __restrict__ ew2, const float* __restrict__ eb2,
    const float* __restrict__ bng, const float* __restrict__ bnb,
    const float* __restrict__ pc1w, const float* __restrict__ pc1b,
    const float* __restrict__ pc2w, const float* __restrict__ pc2b,
    const float* __restrict__ pc3w, const float* __restrict__ pc3b,
    const float* __restrict__ pc4w, const float* __restrict__ pc4b,
    const float* __restrict__ pc5w, const float* __restrict__ pc5b,
    const float* __restrict__ plw,  const float* __restrict__ plb,
    const float* __restrict__ dc1w, const float* __restrict__ dc1b,
    const float* __restrict__ dc2w, const float* __restrict__ dc2b,
    const float* __restrict__ dc3w, const float* __restrict__ dc3b,
    const float* __restrict__ dc4w, const float* __restrict__ dc4b,
    const float* __restrict__ dl1w, const float* __restrict__ dl1b,
    const float* __restrict__ dl2w, const float* __restrict__ dl2b,
    const float* __restrict__ dl3w, const float* __restrict__ dl3b,
    float* __restrict__ out,
    float* __restrict__ partials, float* __restrict__ bnp,
    float* __restrict__ pc1i, float* __restrict__ pc2s,
    float* __restrict__ pc5s, float* __restrict__ dl1s,
    float* __restrict__ crt,
    int B, int nblk)
{
    int tid = threadIdx.x;
    int bid = blockIdx.x;
    int gsz = gridDim.x;
    bool multi = nblk > gsz;
    cg::grid_group gg = cg::this_grid();

    __shared__ float wsum[4][32];
    __shared__ double tot[32];

    float zr[16];

    // phase 1: encoder + stats (+ z spill only in multi mode)
    for (int chunk = bid; chunk < nblk; chunk += gsz) {
        int i = chunk * 256 + tid;
        bool valid = i < B;
        encoder_z(x, i, valid, ew1, eb1, ew2, eb2, zr);
        if (multi && valid) {
            float4* zp = reinterpret_cast<float4*>(crt + (size_t)i * 16);
            zp[0] = make_float4(zr[0],  zr[1],  zr[2],  zr[3]);
            zp[1] = make_float4(zr[4],  zr[5],  zr[6],  zr[7]);
            zp[2] = make_float4(zr[8],  zr[9],  zr[10], zr[11]);
            zp[3] = make_float4(zr[12], zr[13], zr[14], zr[15]);
        }
        block_stats(zr, tid, chunk, wsum, partials);
    }
    if (bid == 0) swizzle_weights(tid, pc1w, pc2w, pc5w, dl1w, pc1i, pc2s, pc5s, dl1s);

    gg.sync();

    // phase 2: block 0 reduces partials -> bnp
    if (bid == 0) {
        int q = tid >> 3, k = tid & 7;
        int chunk = (nblk + 7) / 8;
        int j0 = k * chunk;
        int j1 = j0 + chunk; if (j1 > nblk) j1 = nblk;
        double s = 0.0;
        for (int j = j0; j < j1; ++j) s += (double)partials[(size_t)j * 32 + q];
        s += __shfl_xor(s, 4);
        s += __shfl_xor(s, 2);
        s += __shfl_xor(s, 1);
        if (k == 0) tot[q] = s;
        __syncthreads();
        if (tid < 16) {
            double mu  = tot[tid] / (double)B;
            double var = tot[16 + tid] / (double)B - mu * mu;
            double a = (double)bng[tid] / sqrt(var + 1e-5);
            double b = (double)bnb[tid] - mu * a;
            bnp[tid]      = (float)a;
            bnp[16 + tid] = (float)b;
        }
    }

    gg.sync();

    // phase 3: main pipeline (z from registers in non-multi mode)
    for (int chunk = bid; chunk < nblk; chunk += gsz) {
        int i = chunk * 256 + tid;
        if (i >= B) continue;
        float z[16];
        if (multi) {
            const float4* zp = reinterpret_cast<const float4*>(crt + (size_t)i * 16);
#pragma unroll
            for (int q = 0; q < 4; ++q) {
                float4 v = zp[q];
                z[4*q+0] = v.x; z[4*q+1] = v.y; z[4*q+2] = v.z; z[4*q+3] = v.w;
            }
        } else {
#pragma unroll
            for (int o = 0; o < 16; ++o) z[o] = zr[o];
        }
        pipeline_body(i, z, crt, fading, noise, bnp,
                      pc1i, pc1b, pc2s, pc2b, pc3w, pc3b, pc4w, pc4b, pc5s, pc5b,
                      plw, plb, dc1w, dc1b, dc2w, dc2b, dc3w, dc3b, dc4w, dc4b,
                      dl1s, dl1b, dl2w, dl2b, dl3w, dl3b, out);
    }
}

// ===================== fallback 3-kernel path (r14, proven 225 us) =====================

__global__ __launch_bounds__(256) void kAW(const float* __restrict__ x,
                                           const float* __restrict__ ew1, const float* __restrict__ eb1,
                                           const float* __restrict__ ew2, const float* __restrict__ eb2,
                                           float* __restrict__ partials, float* __restrict__ zout, int B,
                                           const float* __restrict__ pc1w, const float* __restrict__ pc2w,
                                           const float* __restrict__ pc5w, const float* __restrict__ dl1w,
                                           float* __restrict__ pc1i, float* __restrict__ pc2s,
                                           float* __restrict__ pc5s, float* __restrict__ dl1s)
{
    int tid = threadIdx.x;
    if (blockIdx.x == gridDim.x - 1) {
        swizzle_weights(tid, pc1w, pc2w, pc5w, dl1w, pc1i, pc2s, pc5s, dl1s);
        return;
    }
    __shared__ float wsum[4][32];
    int i = blockIdx.x * 256 + tid;
    bool valid = i < B;
    float z[16];
    encoder_z(x, i, valid, ew1, eb1, ew2, eb2, z);
    if (valid) {
        float4* zp = reinterpret_cast<float4*>(zout + (size_t)i * 16);
        zp[0] = make_float4(z[0],  z[1],  z[2],  z[3]);
        zp[1] = make_float4(z[4],  z[5],  z[6],  z[7]);
        zp[2] = make_float4(z[8],  z[9],  z[10], z[11]);
        zp[3] = make_float4(z[12], z[13], z[14], z[15]);
    }
    block_stats(z, tid, blockIdx.x, wsum, partials);
}

__global__ __launch_bounds__(256) void kB(const float* __restrict__ partials, int nblk, int B,
                                          const float* __restrict__ bng, const float* __restrict__ bnb,
                                          float* __restrict__ bnp)
{
    int tid = threadIdx.x;
    int q = tid >> 3, k = tid & 7;
    int chunk = (nblk + 7) / 8;
    int j0 = k * chunk;
    int j1 = j0 + chunk; if (j1 > nblk) j1 = nblk;
    double s = 0.0;
    for (int j = j0; j < j1; ++j) s += (double)partials[(size_t)j * 32 + q];
    s += __shfl_xor(s, 4);
    s += __shfl_xor(s, 2);
    s += __shfl_xor(s, 1);
    __shared__ double tot[32];
    if (k == 0) tot[q] = s;
    __syncthreads();
    if (tid < 16) {
        double mu  = tot[tid] / (double)B;
        double var = tot[16 + tid] / (double)B - mu * mu;
        double a = (double)bng[tid] / sqrt(var + 1e-5);
        double b = (double)bnb[tid] - mu * a;
        bnp[tid]      = (float)a;
        bnp[16 + tid] = (float)b;
    }
}

__global__ __launch_bounds__(256) void kF(float* __restrict__ crt,
    const float* __restrict__ fading, const float* __restrict__ noise,
    const float* __restrict__ bnp,
    const float* __restrict__ pc1i, const float* __restrict__ pc1b,
    const float* __restrict__ pc2s, const float* __restrict__ pc2b,
    const float* __restrict__ pc3w, const float* __restrict__ pc3b,
    const float* __restrict__ pc4w, const float* __restrict__ pc4b,
    const float* __restrict__ pc5s, const float* __restrict__ pc5b,
    const float* __restrict__ plw,  const float* __restrict__ plb,
    const float* __restrict__ dc1w, const float* __restrict__ dc1b,
    const float* __restrict__ dc2w, const float* __restrict__ dc2b,
    const float* __restrict__ dc3w, const float* __restrict__ dc3b,
    const float* __restrict__ dc4w, const float* __restrict__ dc4b,
    const float* __restrict__ dl1s, const float* __restrict__ dl1b,
    const float* __restrict__ dl2w, const float* __restrict__ dl2b,
    const float* __restrict__ dl3w, const float* __restrict__ dl3b,
    float* __restrict__ out, int B)
{
    int i = blockIdx.x * 256 + threadIdx.x;
    if (i >= B) return;
    float z[16];
    {
        const float4* zp = reinterpret_cast<const float4*>(crt + (size_t)i * 16);
#pragma unroll
        for (int q = 0; q < 4; ++q) {
            float4 v = zp[q];
            z[4*q+0] = v.x; z[4*q+1] = v.y; z[4*q+2] = v.z; z[4*q+3] = v.w;
        }
    }
    pipeline_body(i, z, crt, fading, noise, bnp,
                  pc1i, pc1b, pc2s, pc2b, pc3w, pc3b, pc4w, pc4b, pc5s, pc5b,
                  plw, plb, dc1w, dc1b, dc2w, dc2b, dc3w, dc3b, dc4w, dc4b,
                  dl1s, dl1b, dl2w, dl2b, dl3w, dl3b, out);
}

extern "C" void kernel_launch(void* const* d_in, const int* in_sizes, int n_in,
                              void* d_out, int out_size, void* d_ws, size_t ws_size,
                              hipStream_t stream)
{
    const float* x      = (const float*)d_in[0];
    const float* noise  = (const float*)d_in[1];
    const float* fading = (const float*)d_in[2];
    const float* ew1  = (const float*)d_in[3];
    const float* eb1  = (const float*)d_in[4];
    const float* ew2  = (const float*)d_in[5];
    const float* eb2  = (const float*)d_in[6];
    const float* bng  = (const float*)d_in[7];
    const float* bnb  = (const float*)d_in[8];
    const float* pc1w = (const float*)d_in[9];
    const float* pc1b = (const float*)d_in[10];
    const float* pc2w = (const float*)d_in[11];
    const float* pc2b = (const float*)d_in[12];
    const float* pc3w = (const float*)d_in[13];
    const float* pc3b = (const float*)d_in[14];
    const float* pc4w = (const float*)d_in[15];
    const float* pc4b = (const float*)d_in[16];
    const float* pc5w = (const float*)d_in[17];
    const float* pc5b = (const float*)d_in[18];
    const float* plw  = (const float*)d_in[19];
    const float* plb  = (const float*)d_in[20];
    const float* dc1w = (const float*)d_in[21];
    const float* dc1b = (const float*)d_in[22];
    const float* dc2w = (const float*)d_in[23];
    const float* dc2b = (const float*)d_in[24];
    const float* dc3w = (const float*)d_in[25];
    const float* dc3b = (const float*)d_in[26];
    const float* dc4w = (const float*)d_in[27];
    const float* dc4b = (const float*)d_in[28];
    const float* dl1w = (const float*)d_in[29];
    const float* dl1b = (const float*)d_in[30];
    const float* dl2w = (const float*)d_in[31];
    const float* dl2b = (const float*)d_in[32];
    const float* dl3w = (const float*)d_in[33];
    const float* dl3b = (const float*)d_in[34];

    int B = in_sizes[0] / 16;
    int nblk = (B + 255) / 256;

    float* partials = (float*)d_ws;                    // nblk*32
    float* bnp  = partials + (size_t)nblk * 32;        // 32
    float* pc2s = bnp + 32;                            // 512
    float* pc5s = pc2s + 512;                          // 768
    float* dl1s = pc5s + 768;                          // 1024
    float* pc1i = dl1s + 1024;                         // 128
    float* crt  = pc1i + 128;                          // B*16

    float* outp = (float*)d_out;

    // size the cooperative grid from actual occupancy (natural VGPR, no clamp)
    int blocksPerCU = 0;
    hipError_t qerr = hipOccupancyMaxActiveBlocksPerMultiprocessor(&blocksPerCU, (const void*)kFC, 256, 0);
    int maxCoop = (qerr == hipSuccess) ? blocksPerCU * 256 : 0;
    int grid = nblk < maxCoop ? nblk : maxCoop;

    bool launched = false;
    if (grid > 0) {
        void* params[] = {
            (void*)&x, (void*)&noise, (void*)&fading,
            (void*)&ew1, (void*)&eb1, (void*)&ew2, (void*)&eb2,
            (void*)&bng, (void*)&bnb,
            (void*)&pc1w, (void*)&pc1b, (void*)&pc2w, (void*)&pc2b,
            (void*)&pc3w, (void*)&pc3b, (void*)&pc4w, (void*)&pc4b,
            (void*)&pc5w, (void*)&pc5b, (void*)&plw, (void*)&plb,
            (void*)&dc1w, (void*)&dc1b, (void*)&dc2w, (void*)&dc2b,
            (void*)&dc3w, (void*)&dc3b, (void*)&dc4w, (void*)&dc4b,
            (void*)&dl1w, (void*)&dl1b, (void*)&dl2w, (void*)&dl2b,
            (void*)&dl3w, (void*)&dl3b,
            (void*)&outp,
            (void*)&partials, (void*)&bnp,
            (void*)&pc1i, (void*)&pc2s, (void*)&pc5s, (void*)&dl1s,
            (void*)&crt,
            (void*)&B, (void*)&nblk
        };
        hipError_t err = hipLaunchCooperativeKernel((void*)kFC, dim3(grid), dim3(256),
                                                    params, 0, stream);
        launched = (err == hipSuccess);
        if (!launched) (void)hipGetLastError();   // clear sticky error
    }

    if (!launched) {
        // deterministic fallback: proven 3-kernel path
        kAW<<<nblk + 1, 256, 0, stream>>>(x, ew1, eb1, ew2, eb2, partials, crt, B,
                                          pc1w, pc2w, pc5w, dl1w,
                                          pc1i, pc2s, pc5s, dl1s);
        kB<<<1, 256, 0, stream>>>(partials, nblk, B, bng, bnb, bnp);
        kF<<<nblk, 256, 0, stream>>>(crt, fading, noise, bnp,
                                     pc1i, pc1b, pc2s, pc2b, pc3w, pc3b, pc4w, pc4b, pc5s, pc5b,
                                     plw, plb,
                                     dc1w, dc1b, dc2w, dc2b, dc3w, dc3b, dc4w, dc4b,
                                     dl1s, dl1b, dl2w, dl2b, dl3w, dl3b,
                                     (float*)d_out, B);
    }
}